// Round 1
// baseline (1503.194 us; speedup 1.0000x reference)
//
#include <hip/hip_runtime.h>
#include <math.h>

#define H 10
#define BATCH 16384
#define NPAIRS 1024   // T/2
#define EPW 6         // elements (sequences) per 64-lane wave, 60 active lanes

__device__ __forceinline__ float fast_rcp(float x) { return __builtin_amdgcn_rcpf(x); }
__device__ __forceinline__ float sigm(float x) { return fast_rcp(1.0f + __expf(-x)); }
__device__ __forceinline__ float tanh_fast(float x) {
    float ax = __builtin_fabsf(x);
    float e  = __expf(-2.0f * ax);            // in (0,1], no overflow
    float t  = (1.0f - e) * fast_rcp(1.0f + e);
    return __builtin_copysignf(t, x);
}

__global__ void __launch_bounds__(64, 3)
lstm_kernel(const float* __restrict__ x,
            const float* __restrict__ WihA, const float* __restrict__ WhhA,
            const float* __restrict__ bihA, const float* __restrict__ bhhA,
            const float* __restrict__ WihB, const float* __restrict__ WhhB,
            const float* __restrict__ bihB, const float* __restrict__ bhhB,
            const float* __restrict__ Wlin, const float* __restrict__ blin,
            float* __restrict__ out)
{
    const int lane    = threadIdx.x;          // block = 1 wave = 64 lanes
    const int e_local = lane / H;             // 0..6 (6 => inactive spare lanes)
    const int j       = lane - e_local * H;   // hidden unit owned by this lane
    const bool active = lane < EPW * H;
    const int elem    = blockIdx.x * EPW + e_local;
    const bool valid  = active && (elem < BATCH);
    const int jj      = active ? j : 0;       // clamped for safe weight loads
    const int elem_c  = valid ? elem : 0;     // clamped for safe x loads

    // Per-lane weights in registers: lane j needs gate rows {j, H+j, 2H+j, 3H+j}.
    // 80 (Whh) + 12 (Wih) + 8 (bias) = 100 VGPRs; no LDS needed.
    float wA[4][H], wB[4][H];
    float bA[4], bB[4], wxA0[4], wxA1[4], wxB[4];
#pragma unroll
    for (int g = 0; g < 4; ++g) {
        const int row = g * H + jj;
        bA[g]   = bihA[row] + bhhA[row];
        bB[g]   = bihB[row] + bhhB[row];
        wxA0[g] = WihA[row * 2 + 0];
        wxA1[g] = WihA[row * 2 + 1];
        wxB[g]  = WihB[row];
#pragma unroll
        for (int k = 0; k < H; ++k) {
            wA[g][k] = WhhA[row * H + k];
            wB[g][k] = WhhB[row * H + k];
        }
    }

    const int base4 = (e_local * H) << 2;     // bpermute byte addr of group base
    const float4* __restrict__ xr = (const float4*)x + (size_t)elem_c * NPAIRS;

    float h = 0.0f, c = 0.0f;
    for (int p = 0; p < NPAIRS; ++p) {
        const float4 xp = xr[p];  // x[e,2p,0], x[e,2p,1], x[e,2p+1,0], x[e,2p+1,1]

        // ---- cell B: input = x[:, 2p, :1] ----
        float g0 = fmaf(wxB[0], xp.x, bB[0]);   // i
        float g1 = fmaf(wxB[1], xp.x, bB[1]);   // f
        float g2 = fmaf(wxB[2], xp.x, bB[2]);   // g
        float g3 = fmaf(wxB[3], xp.x, bB[3]);   // o
#pragma unroll
        for (int k = 0; k < H; ++k) {
            const float hk = __int_as_float(
                __builtin_amdgcn_ds_bpermute(base4 + (k << 2), __float_as_int(h)));
            g0 = fmaf(wB[0][k], hk, g0);
            g1 = fmaf(wB[1][k], hk, g1);
            g2 = fmaf(wB[2][k], hk, g2);
            g3 = fmaf(wB[3][k], hk, g3);
        }
        c = sigm(g1) * c + sigm(g0) * tanh_fast(g2);
        h = sigm(g3) * tanh_fast(c);

        // ---- cell A: input = x[:, 2p+1, :] ----
        g0 = fmaf(wxA1[0], xp.w, fmaf(wxA0[0], xp.z, bA[0]));
        g1 = fmaf(wxA1[1], xp.w, fmaf(wxA0[1], xp.z, bA[1]));
        g2 = fmaf(wxA1[2], xp.w, fmaf(wxA0[2], xp.z, bA[2]));
        g3 = fmaf(wxA1[3], xp.w, fmaf(wxA0[3], xp.z, bA[3]));
#pragma unroll
        for (int k = 0; k < H; ++k) {
            const float hk = __int_as_float(
                __builtin_amdgcn_ds_bpermute(base4 + (k << 2), __float_as_int(h)));
            g0 = fmaf(wA[0][k], hk, g0);
            g1 = fmaf(wA[1][k], hk, g1);
            g2 = fmaf(wA[2][k], hk, g2);
            g3 = fmaf(wA[3][k], hk, g3);
        }
        c = sigm(g1) * c + sigm(g0) * tanh_fast(g2);
        h = sigm(g3) * tanh_fast(c);
    }

    // ---- output: sigmoid(h . Wlin + blin), reduce across the 10-lane group ----
    const float v = Wlin[jj] * h;
    float s = v;
#pragma unroll
    for (int k = 1; k < H; ++k) {
        s += __int_as_float(
            __builtin_amdgcn_ds_bpermute(base4 + (k << 2), __float_as_int(v)));
    }
    if (valid && j == 0) out[elem] = sigm(s + blin[0]);
}

extern "C" void kernel_launch(void* const* d_in, const int* in_sizes, int n_in,
                              void* d_out, int out_size, void* d_ws, size_t ws_size,
                              hipStream_t stream) {
    const float* x    = (const float*)d_in[0];
    const float* WihA = (const float*)d_in[1];
    const float* WhhA = (const float*)d_in[2];
    const float* bihA = (const float*)d_in[3];
    const float* bhhA = (const float*)d_in[4];
    const float* WihB = (const float*)d_in[5];
    const float* WhhB = (const float*)d_in[6];
    const float* bihB = (const float*)d_in[7];
    const float* bhhB = (const float*)d_in[8];
    const float* Wlin = (const float*)d_in[9];
    const float* blin = (const float*)d_in[10];
    float* out = (float*)d_out;

    const int grid = (BATCH + EPW - 1) / EPW;  // 2731 one-wave blocks
    hipLaunchKernelGGL(lstm_kernel, dim3(grid), dim3(64), 0, stream,
                       x, WihA, WhhA, bihA, bhhA, WihB, WhhB, bihB, bhhB,
                       Wlin, blin, out);
}

// Round 2
// 1230.958 us; speedup vs baseline: 1.2212x; 1.2212x over previous
//
#include <hip/hip_runtime.h>
#include <math.h>

#define H 10
#define BATCH 16384
#define NPAIRS 1024   // T/2
#define EPW 6         // sequences per 64-lane wave, 60 active lanes

#define LOG2E 1.44269504088896340736f

#if __has_builtin(__builtin_amdgcn_exp2f)
#define EXP2(x) __builtin_amdgcn_exp2f(x)
#else
#define EXP2(x) exp2f(x)
#endif

__device__ __forceinline__ float fast_rcp(float x) { return __builtin_amdgcn_rcpf(x); }

// y accumulated with weights pre-scaled by -log2e: sigmoid(x) = 1/(1+2^y)
__device__ __forceinline__ float sigm_pre(float y) {
    return fast_rcp(1.0f + EXP2(y));
}
// y accumulated with weights pre-scaled by +2*log2e: tanh(x) = sign(y)*(1-2^-|y|)/(1+2^-|y|)
__device__ __forceinline__ float tanh_pre(float y) {
    float e = EXP2(-__builtin_fabsf(y));   // -abs folds into instruction modifiers
    float t = (1.0f - e) * fast_rcp(1.0f + e);
    return __builtin_copysignf(t, y);
}
// raw-argument tanh (for c): fold the scale here
__device__ __forceinline__ float tanh_raw(float x) {
    return tanh_pre((2.0f * LOG2E) * x);
}

__global__ void __launch_bounds__(64, 3)
lstm_kernel(const float* __restrict__ x,
            const float* __restrict__ WihA, const float* __restrict__ WhhA,
            const float* __restrict__ bihA, const float* __restrict__ bhhA,
            const float* __restrict__ WihB, const float* __restrict__ WhhB,
            const float* __restrict__ bihB, const float* __restrict__ bhhB,
            const float* __restrict__ Wlin, const float* __restrict__ blin,
            float* __restrict__ out)
{
    const int lane    = threadIdx.x;          // block = 1 wave
    const int e_local = lane / H;             // 0..6 (6 => spare lanes)
    const int j       = lane - e_local * H;   // hidden unit owned by this lane
    const bool active = lane < EPW * H;
    const int elem    = blockIdx.x * EPW + e_local;
    const bool valid  = active && (elem < BATCH);
    const int jj      = active ? j : 0;
    const int elem_c  = valid ? elem : 0;

    // Per-lane weights in registers: lane j owns gate rows {j, H+j, 2H+j, 3H+j}.
    // Pre-scaled: sigmoid gates (i,f,o) by -log2e, tanh gate (g) by +2log2e.
    float wA[4][H], wB[4][H];
    float bA[4], bB[4], wxA0[4], wxA1[4], wxB[4];
#pragma unroll
    for (int g = 0; g < 4; ++g) {
        const float s = (g == 2) ? (2.0f * LOG2E) : (-LOG2E);
        const int row = g * H + jj;
        bA[g]   = s * (bihA[row] + bhhA[row]);
        bB[g]   = s * (bihB[row] + bhhB[row]);
        wxA0[g] = s * WihA[row * 2 + 0];
        wxA1[g] = s * WihA[row * 2 + 1];
        wxB[g]  = s * WihB[row];
#pragma unroll
        for (int k = 0; k < H; ++k) {
            wA[g][k] = s * WhhA[row * H + k];
            wB[g][k] = s * WhhB[row * H + k];
        }
    }
    // Pin all weights into VGPRs: opaque to the compiler => cannot be
    // rematerialized as in-loop reloads (round-1 showed VGPR=64 + per-iter
    // reload behavior without this).
#pragma unroll
    for (int g = 0; g < 4; ++g) {
        asm volatile("" : "+v"(bA[g]), "+v"(bB[g]), "+v"(wxA0[g]),
                          "+v"(wxA1[g]), "+v"(wxB[g]));
#pragma unroll
        for (int k = 0; k < H; ++k) {
            asm volatile("" : "+v"(wA[g][k]), "+v"(wB[g][k]));
        }
    }

    const int base4 = (e_local * H) << 2;     // bpermute byte addr of group base
    const float4* __restrict__ xr = (const float4*)x + (size_t)elem_c * NPAIRS;

    float h = 0.0f, c = 0.0f;
    float4 xp = xr[0];                        // prefetched current pair
    for (int p = 0; p < NPAIRS; ++p) {
        const int pn = (p + 1 < NPAIRS) ? (p + 1) : p;
        const float4 xnext = xr[pn];          // off the critical h->h chain

        // ---- cell B: input = x[:, 2p, :1] ----
        float g0 = fmaf(wxB[0], xp.x, bB[0]);   // i (scaled -log2e)
        float g1 = fmaf(wxB[1], xp.x, bB[1]);   // f
        float g2 = fmaf(wxB[2], xp.x, bB[2]);   // g (scaled +2log2e)
        float g3 = fmaf(wxB[3], xp.x, bB[3]);   // o
#pragma unroll
        for (int k = 0; k < H; ++k) {
            const float hk = __int_as_float(
                __builtin_amdgcn_ds_bpermute(base4 + (k << 2), __float_as_int(h)));
            g0 = fmaf(wB[0][k], hk, g0);
            g1 = fmaf(wB[1][k], hk, g1);
            g2 = fmaf(wB[2][k], hk, g2);
            g3 = fmaf(wB[3][k], hk, g3);
        }
        c = sigm_pre(g1) * c + sigm_pre(g0) * tanh_pre(g2);
        h = sigm_pre(g3) * tanh_raw(c);

        // ---- cell A: input = x[:, 2p+1, :] ----
        g0 = fmaf(wxA1[0], xp.w, fmaf(wxA0[0], xp.z, bA[0]));
        g1 = fmaf(wxA1[1], xp.w, fmaf(wxA0[1], xp.z, bA[1]));
        g2 = fmaf(wxA1[2], xp.w, fmaf(wxA0[2], xp.z, bA[2]));
        g3 = fmaf(wxA1[3], xp.w, fmaf(wxA0[3], xp.z, bA[3]));
#pragma unroll
        for (int k = 0; k < H; ++k) {
            const float hk = __int_as_float(
                __builtin_amdgcn_ds_bpermute(base4 + (k << 2), __float_as_int(h)));
            g0 = fmaf(wA[0][k], hk, g0);
            g1 = fmaf(wA[1][k], hk, g1);
            g2 = fmaf(wA[2][k], hk, g2);
            g3 = fmaf(wA[3][k], hk, g3);
        }
        c = sigm_pre(g1) * c + sigm_pre(g0) * tanh_pre(g2);
        h = sigm_pre(g3) * tanh_raw(c);

        xp = xnext;
    }

    // ---- output: sigmoid(h . Wlin + blin), reduce across the 10-lane group ----
    const float v = Wlin[jj] * h;
    float s = v;
#pragma unroll
    for (int k = 1; k < H; ++k) {
        s += __int_as_float(
            __builtin_amdgcn_ds_bpermute(base4 + (k << 2), __float_as_int(v)));
    }
    if (valid && j == 0) {
        const float y = s + blin[0];
        out[elem] = fast_rcp(1.0f + EXP2(-LOG2E * y));
    }
}

extern "C" void kernel_launch(void* const* d_in, const int* in_sizes, int n_in,
                              void* d_out, int out_size, void* d_ws, size_t ws_size,
                              hipStream_t stream) {
    const float* x    = (const float*)d_in[0];
    const float* WihA = (const float*)d_in[1];
    const float* WhhA = (const float*)d_in[2];
    const float* bihA = (const float*)d_in[3];
    const float* bhhA = (const float*)d_in[4];
    const float* WihB = (const float*)d_in[5];
    const float* WhhB = (const float*)d_in[6];
    const float* bihB = (const float*)d_in[7];
    const float* bhhB = (const float*)d_in[8];
    const float* Wlin = (const float*)d_in[9];
    const float* blin = (const float*)d_in[10];
    float* out = (float*)d_out;

    const int grid = (BATCH + EPW - 1) / EPW;  // 2731 one-wave blocks
    hipLaunchKernelGGL(lstm_kernel, dim3(grid), dim3(64), 0, stream,
                       x, WihA, WhhA, bihA, bhhA, WihB, WhhB, bihB, bhhB,
                       Wlin, blin, out);
}

// Round 3
// 1119.947 us; speedup vs baseline: 1.3422x; 1.0991x over previous
//
#include <hip/hip_runtime.h>
#include <math.h>

#define H 10
#define BATCH 16384
#define NPAIRS 1024   // T/2
#define EPW 6         // sequences per 64-lane wave, 60 active lanes

#define LOG2E 1.44269504088896340736f

#if __has_builtin(__builtin_amdgcn_exp2f)
#define EXP2(x) __builtin_amdgcn_exp2f(x)
#else
#define EXP2(x) exp2f(x)
#endif

__device__ __forceinline__ float fast_rcp(float x) { return __builtin_amdgcn_rcpf(x); }

__global__ void __launch_bounds__(64, 2)
lstm_kernel(const float* __restrict__ x,
            const float* __restrict__ WihA, const float* __restrict__ WhhA,
            const float* __restrict__ bihA, const float* __restrict__ bhhA,
            const float* __restrict__ WihB, const float* __restrict__ WhhB,
            const float* __restrict__ bihB, const float* __restrict__ bhhB,
            const float* __restrict__ Wlin, const float* __restrict__ blin,
            float* __restrict__ out)
{
    const int lane    = threadIdx.x;          // block = 1 wave
    const int e_local = lane / H;             // 0..6 (6 => spare lanes)
    const int j       = lane - e_local * H;   // hidden unit owned by this lane
    const bool active = lane < EPW * H;
    const int elem    = blockIdx.x * EPW + e_local;
    const bool valid  = active && (elem < BATCH);
    const int jj      = active ? j : 0;
    const int elem_c  = valid ? elem : 0;

    // Per-lane weights in registers: lane j owns gate rows {j, H+j, 2H+j, 3H+j}.
    // Pre-scaled: sigmoid gates (i,f,o) by -log2e, tanh gate (g) by +2log2e,
    // so all activations use raw exp2.
    float wA[4][H], wB[4][H];
    float bA[4], bB[4], wxA0[4], wxA1[4], wxB[4];
#pragma unroll
    for (int g = 0; g < 4; ++g) {
        const float s = (g == 2) ? (2.0f * LOG2E) : (-LOG2E);
        const int row = g * H + jj;
        bA[g]   = s * (bihA[row] + bhhA[row]);
        bB[g]   = s * (bihB[row] + bhhB[row]);
        wxA0[g] = s * WihA[row * 2 + 0];
        wxA1[g] = s * WihA[row * 2 + 1];
        wxB[g]  = s * WihB[row];
#pragma unroll
        for (int k = 0; k < H; ++k) {
            wA[g][k] = s * WhhA[row * H + k];
            wB[g][k] = s * WhhB[row * H + k];
        }
    }
    // Pin weights as opaque register values (defeats in-loop rematerialization).
    // launch_bounds(64,2) gives a 256-VGPR budget so these can be ARCH VGPRs,
    // not AGPR-parked (round-2: VGPR=72 => ~80 v_accvgpr_read per pair).
#pragma unroll
    for (int g = 0; g < 4; ++g) {
        asm volatile("" : "+v"(bA[g]), "+v"(bB[g]), "+v"(wxA0[g]),
                          "+v"(wxA1[g]), "+v"(wxB[g]));
#pragma unroll
        for (int k = 0; k < H; ++k) {
            asm volatile("" : "+v"(wA[g][k]), "+v"(wB[g][k]));
        }
    }

    const int base4 = (e_local * H) << 2;     // bpermute byte addr of group base
    const float4* __restrict__ xr = (const float4*)x + (size_t)elem_c * NPAIRS;

    float h = 0.0f, c = 0.0f;
    float4 xp = xr[0];                        // prefetched current pair

#pragma unroll 2
    for (int p = 0; p < NPAIRS; ++p) {
        const int pn = (p + 1 < NPAIRS) ? (p + 1) : p;
        const float4 xnext = xr[pn];          // off the critical h->h chain

        // ================= cell B: input = x[:, 2p, :1] =================
        {
            float y0 = fmaf(wxB[0], xp.x, bB[0]);   // i (scaled -log2e)
            float y1 = fmaf(wxB[1], xp.x, bB[1]);   // f (scaled -log2e)
            float y2 = fmaf(wxB[2], xp.x, bB[2]);   // g (scaled +2log2e)
            float y3 = fmaf(wxB[3], xp.x, bB[3]);   // o (scaled -log2e)
#pragma unroll
            for (int k = 0; k < H; ++k) {
                const float hk = __int_as_float(
                    __builtin_amdgcn_ds_bpermute(base4 + (k << 2), __float_as_int(h)));
                y0 = fmaf(wB[0][k], hk, y0);
                y1 = fmaf(wB[1][k], hk, y1);
                y2 = fmaf(wB[2][k], hk, y2);
                y3 = fmaf(wB[3][k], hk, y3);
            }
            // fused: sigm(f)*c + sigm(i)*tanh(g)   [single rcp for i*g term]
            const float ef = EXP2(y1);
            const float ei = EXP2(y0);
            const float eg = EXP2(-__builtin_fabsf(y2));
            const float sf = fast_rcp(1.0f + ef);
            const float d1 = (1.0f + ei) * (1.0f + eg);
            const float it = __builtin_copysignf((1.0f - eg) * fast_rcp(d1), y2);
            const float cn = fmaf(sf, c, it);
            // fused: sigm(o)*tanh(c)               [single rcp]
            const float eo = EXP2(y3);
            const float ec = EXP2((-2.0f * LOG2E) * __builtin_fabsf(cn));
            const float d2 = (1.0f + eo) * (1.0f + ec);
            h = __builtin_copysignf((1.0f - ec) * fast_rcp(d2), cn);
            c = cn;
        }

        // ================= cell A: input = x[:, 2p+1, :] =================
        {
            float y0 = fmaf(wxA1[0], xp.w, fmaf(wxA0[0], xp.z, bA[0]));
            float y1 = fmaf(wxA1[1], xp.w, fmaf(wxA0[1], xp.z, bA[1]));
            float y2 = fmaf(wxA1[2], xp.w, fmaf(wxA0[2], xp.z, bA[2]));
            float y3 = fmaf(wxA1[3], xp.w, fmaf(wxA0[3], xp.z, bA[3]));
#pragma unroll
            for (int k = 0; k < H; ++k) {
                const float hk = __int_as_float(
                    __builtin_amdgcn_ds_bpermute(base4 + (k << 2), __float_as_int(h)));
                y0 = fmaf(wA[0][k], hk, y0);
                y1 = fmaf(wA[1][k], hk, y1);
                y2 = fmaf(wA[2][k], hk, y2);
                y3 = fmaf(wA[3][k], hk, y3);
            }
            const float ef = EXP2(y1);
            const float ei = EXP2(y0);
            const float eg = EXP2(-__builtin_fabsf(y2));
            const float sf = fast_rcp(1.0f + ef);
            const float d1 = (1.0f + ei) * (1.0f + eg);
            const float it = __builtin_copysignf((1.0f - eg) * fast_rcp(d1), y2);
            const float cn = fmaf(sf, c, it);
            const float eo = EXP2(y3);
            const float ec = EXP2((-2.0f * LOG2E) * __builtin_fabsf(cn));
            const float d2 = (1.0f + eo) * (1.0f + ec);
            h = __builtin_copysignf((1.0f - ec) * fast_rcp(d2), cn);
            c = cn;
        }

        xp = xnext;
    }

    // ---- output: sigmoid(h . Wlin + blin), reduce across the 10-lane group ----
    const float v = Wlin[jj] * h;
    float s = v;
#pragma unroll
    for (int k = 1; k < H; ++k) {
        s += __int_as_float(
            __builtin_amdgcn_ds_bpermute(base4 + (k << 2), __float_as_int(v)));
    }
    if (valid && j == 0) {
        const float y = s + blin[0];
        out[elem] = fast_rcp(1.0f + EXP2(-LOG2E * y));
    }
}

extern "C" void kernel_launch(void* const* d_in, const int* in_sizes, int n_in,
                              void* d_out, int out_size, void* d_ws, size_t ws_size,
                              hipStream_t stream) {
    const float* x    = (const float*)d_in[0];
    const float* WihA = (const float*)d_in[1];
    const float* WhhA = (const float*)d_in[2];
    const float* bihA = (const float*)d_in[3];
    const float* bhhA = (const float*)d_in[4];
    const float* WihB = (const float*)d_in[5];
    const float* WhhB = (const float*)d_in[6];
    const float* bihB = (const float*)d_in[7];
    const float* bhhB = (const float*)d_in[8];
    const float* Wlin = (const float*)d_in[9];
    const float* blin = (const float*)d_in[10];
    float* out = (float*)d_out;

    const int grid = (BATCH + EPW - 1) / EPW;  // 2731 one-wave blocks
    hipLaunchKernelGGL(lstm_kernel, dim3(grid), dim3(64), 0, stream,
                       x, WihA, WhhA, bihA, bhhA, WihB, WhhB, bihB, bhhB,
                       Wlin, blin, out);
}